// Round 1
// baseline (563.423 us; speedup 1.0000x reference)
//
#include <hip/hip_runtime.h>
#include <hip/hip_bf16.h>
#include <cmath>

#define NT    4096            // B*T tokens
#define CDIM  768
#define HDIM  3072
#define NEXP  8
#define SLOTS (NT * 2)        // top-2 -> 8192 (token,expert) pairs, exact
#define MAXT  72              // max M-tiles: 8192/128 + 8 partial tiles

typedef __bf16 bf16_t;
typedef __bf16 bf16x8 __attribute__((ext_vector_type(8)));
typedef float  f32x4  __attribute__((ext_vector_type(4)));

// ---------- x fp32 -> bf16 ----------
__global__ void convert_x_kernel(const float* __restrict__ x, bf16_t* __restrict__ xb) {
    int i = (blockIdx.x * blockDim.x + threadIdx.x) * 4;
    float4 v = *reinterpret_cast<const float4*>(x + i);
    union { bf16_t h[4]; uint2 u; } un;
    un.h[0] = (bf16_t)v.x; un.h[1] = (bf16_t)v.y;
    un.h[2] = (bf16_t)v.z; un.h[3] = (bf16_t)v.w;
    *reinterpret_cast<uint2*>(xb + i) = un.u;
}

// ---------- W fp32 (E,R,CC) -> bf16 transposed (E,CC,R) ----------
template<int R, int CC>
__global__ void transpose_convert_kernel(const float* __restrict__ in, bf16_t* __restrict__ out) {
    __shared__ float tile[32][33];
    int e = blockIdx.z;
    int c0 = blockIdx.x * 32, r0 = blockIdx.y * 32;
    const float* src = in + (size_t)e * R * CC;
    bf16_t* dst = out + (size_t)e * R * CC;
    int tx = threadIdx.x, ty = threadIdx.y;    // (32,8)
    #pragma unroll
    for (int i = 0; i < 32; i += 8)
        tile[ty + i][tx] = src[(size_t)(r0 + ty + i) * CC + c0 + tx];
    __syncthreads();
    #pragma unroll
    for (int i = 0; i < 32; i += 8)
        dst[(size_t)(c0 + ty + i) * R + r0 + tx] = (bf16_t)tile[tx][ty + i];
}

// ---------- router: fp32 logits, softmax, top-2 ----------
__global__ void router_kernel(const float* __restrict__ x, const float* __restrict__ wg,
                              int* __restrict__ eidx, float* __restrict__ egate,
                              int* __restrict__ counts) {
    int t = blockIdx.x;
    int lane = threadIdx.x;     // 64 = 1 wave
    const float* xr = x + (size_t)t * CDIM;
    float acc[NEXP];
    #pragma unroll
    for (int e = 0; e < NEXP; e++) acc[e] = 0.f;
    for (int c = lane; c < CDIM; c += 64) {
        float xv = xr[c];
        #pragma unroll
        for (int e = 0; e < NEXP; e++) acc[e] += xv * wg[c * NEXP + e];
    }
    #pragma unroll
    for (int e = 0; e < NEXP; e++) {
        #pragma unroll
        for (int off = 32; off > 0; off >>= 1)
            acc[e] += __shfl_xor(acc[e], off, 64);
    }
    if (lane == 0) {
        float mx = acc[0];
        #pragma unroll
        for (int e = 1; e < NEXP; e++) mx = fmaxf(mx, acc[e]);
        float p[NEXP], s = 0.f;
        #pragma unroll
        for (int e = 0; e < NEXP; e++) { p[e] = expf(acc[e] - mx); s += p[e]; }
        float inv = 1.f / s;
        int i0 = 0;
        #pragma unroll
        for (int e = 1; e < NEXP; e++) if (p[e] > p[i0]) i0 = e;   // ties -> lower idx, matches lax.top_k
        int i1 = (i0 == 0) ? 1 : 0;
        #pragma unroll
        for (int e = 0; e < NEXP; e++) if (e != i0 && p[e] > p[i1]) i1 = e;
        eidx[t * 2]     = i0;  eidx[t * 2 + 1]  = i1;
        egate[t * 2]    = p[i0] * inv;
        egate[t * 2 + 1] = p[i1] * inv;
        atomicAdd(&counts[i0], 1);
        atomicAdd(&counts[i1], 1);
    }
}

// ---------- plan: prefix sums + M-tile table (single thread, 72 iters) ----------
__global__ void plan_kernel(const int* __restrict__ counts, int* __restrict__ curs,
                            int* __restrict__ tile_e, int* __restrict__ tile_m0,
                            int* __restrict__ tile_end) {
    if (threadIdx.x != 0 || blockIdx.x != 0) return;
    int off = 0, nt = 0;
    for (int e = 0; e < NEXP; e++) {
        int ne = counts[e];
        curs[e] = off;
        int ntile = (ne + 127) >> 7;
        for (int j = 0; j < ntile; j++) {
            tile_e[nt] = e; tile_m0[nt] = off + j * 128; tile_end[nt] = off + ne; nt++;
        }
        off += ne;
    }
    for (; nt < MAXT; nt++) tile_e[nt] = -1;
}

// ---------- scatter tokens into per-expert contiguous slots ----------
__global__ void scatter_kernel(const int* __restrict__ eidx, const float* __restrict__ egate,
                               int* __restrict__ curs, int* __restrict__ tmap,
                               float* __restrict__ gmap) {
    int t = blockIdx.x * blockDim.x + threadIdx.x;
    if (t >= NT) return;
    #pragma unroll
    for (int s = 0; s < 2; s++) {
        int e = eidx[t * 2 + s];
        int p = atomicAdd(&curs[e], 1);
        tmap[p] = t;
        gmap[p] = egate[t * 2 + s];
    }
}

// ---------- grouped GEMM, 128x128 tile, 4 waves x (4x4) 16x16x32 bf16 MFMA ----------
// FIRST: h[pos][n] = relu(bf16(X[tmap[pos]]) @ W1t[e] + b1[e])   (KDIM=768,  NDIM=3072)
// !FIRST: out[tmap[pos]][n] += gmap[pos] * (h[pos] @ W2t[e] + b2[e]) (KDIM=3072, NDIM=768)
template<int KDIM, int NDIM, bool FIRST>
__global__ __launch_bounds__(256)
void moe_gemm_kernel(const bf16_t* __restrict__ Asrc, const bf16_t* __restrict__ Wt,
                     const float* __restrict__ bias,
                     const int* __restrict__ tile_e, const int* __restrict__ tile_m0,
                     const int* __restrict__ tile_end,
                     const int* __restrict__ tmap, const float* __restrict__ gmap,
                     bf16_t* __restrict__ hout, float* __restrict__ out) {
    int mt = blockIdx.x;
    int e = tile_e[mt];
    if (e < 0) return;
    int m0 = tile_m0[mt];
    int rend = tile_end[mt];
    int n0 = blockIdx.y * 128;

    // padded stride 40 elems (80B): 16B-aligned frag reads, <=2-way bank aliasing (free)
    __shared__ __attribute__((aligned(16))) bf16_t As[128 * 40];
    __shared__ __attribute__((aligned(16))) bf16_t Bs[128 * 40];

    int tid = threadIdx.x;
    const bf16_t* aBase[2];
    const bf16_t* bBase[2];
    bool aValid[2];
    int ldsOff[2];
    #pragma unroll
    for (int it = 0; it < 2; it++) {
        int cid = tid + it * 256;          // 512 chunks of 8 bf16 per tile
        int row = cid >> 2;
        int kk = (cid & 3) << 3;
        ldsOff[it] = row * 40 + kk;
        int pos = m0 + row;
        aValid[it] = pos < rend;
        if (FIRST) {
            int t = aValid[it] ? tmap[pos] : 0;
            aBase[it] = Asrc + (size_t)t * KDIM + kk;
        } else {
            aBase[it] = Asrc + (size_t)(aValid[it] ? pos : 0) * KDIM + kk;
        }
        bBase[it] = Wt + ((size_t)e * NDIM + n0 + row) * KDIM + kk;
    }

    int lane = tid & 63, wid = tid >> 6;
    int wm = (wid >> 1) * 64, wn = (wid & 1) * 64;
    int q = lane >> 4, mr = lane & 15;

    f32x4 acc[4][4];
    #pragma unroll
    for (int i = 0; i < 4; i++)
        #pragma unroll
        for (int j = 0; j < 4; j++)
            acc[i][j] = (f32x4){0.f, 0.f, 0.f, 0.f};

    int aOff = (wm + mr) * 40 + q * 8;
    int bOff = (wn + mr) * 40 + q * 8;

    for (int k0 = 0; k0 < KDIM; k0 += 32) {
        #pragma unroll
        for (int it = 0; it < 2; it++) {
            uint4 av = make_uint4(0u, 0u, 0u, 0u);
            if (aValid[it]) av = *reinterpret_cast<const uint4*>(aBase[it] + k0);
            *reinterpret_cast<uint4*>(&As[ldsOff[it]]) = av;
            *reinterpret_cast<uint4*>(&Bs[ldsOff[it]]) = *reinterpret_cast<const uint4*>(bBase[it] + k0);
        }
        __syncthreads();
        bf16x8 af[4], bfr[4];
        #pragma unroll
        for (int ti = 0; ti < 4; ti++) af[ti]  = *reinterpret_cast<const bf16x8*>(&As[aOff + ti * 16 * 40]);
        #pragma unroll
        for (int tj = 0; tj < 4; tj++) bfr[tj] = *reinterpret_cast<const bf16x8*>(&Bs[bOff + tj * 16 * 40]);
        #pragma unroll
        for (int ti = 0; ti < 4; ti++)
            #pragma unroll
            for (int tj = 0; tj < 4; tj++)
                acc[ti][tj] = __builtin_amdgcn_mfma_f32_16x16x32_bf16(af[ti], bfr[tj], acc[ti][tj], 0, 0, 0);
        __syncthreads();
    }

    // epilogue: D[row=q*4+r][col=mr] per 16x16 tile
    const float* be = bias + (size_t)e * NDIM;
    #pragma unroll
    for (int ti = 0; ti < 4; ti++) {
        #pragma unroll
        for (int r = 0; r < 4; r++) {
            int pos = m0 + wm + ti * 16 + q * 4 + r;
            if (pos < rend) {
                if (FIRST) {
                    bf16_t* hrow = hout + (size_t)pos * NDIM;
                    #pragma unroll
                    for (int tj = 0; tj < 4; tj++) {
                        int gcol = n0 + wn + tj * 16 + mr;
                        float v = acc[ti][tj][r] + be[gcol];
                        hrow[gcol] = (bf16_t)fmaxf(v, 0.f);
                    }
                } else {
                    int t = tmap[pos];
                    float g = gmap[pos];
                    float* orow = out + (size_t)t * NDIM;
                    #pragma unroll
                    for (int tj = 0; tj < 4; tj++) {
                        int gcol = n0 + wn + tj * 16 + mr;
                        atomicAdd(&orow[gcol], g * (acc[ti][tj][r] + be[gcol]));
                    }
                }
            }
        }
    }
}

extern "C" void kernel_launch(void* const* d_in, const int* in_sizes, int n_in,
                              void* d_out, int out_size, void* d_ws, size_t ws_size,
                              hipStream_t stream) {
    const float* x  = (const float*)d_in[0];
    const float* wg = (const float*)d_in[1];
    const float* w1 = (const float*)d_in[2];
    const float* b1 = (const float*)d_in[3];
    const float* w2 = (const float*)d_in[4];
    const float* b2 = (const float*)d_in[5];
    float* out = (float*)d_out;

    char* w = (char*)d_ws;
    size_t off = 0;
    bf16_t* xb  = (bf16_t*)(w + off); off += (size_t)NT * CDIM * 2;             // 6.3 MB
    bf16_t* w1t = (bf16_t*)(w + off); off += (size_t)NEXP * CDIM * HDIM * 2;    // 37.7 MB
    bf16_t* w2t = (bf16_t*)(w + off); off += (size_t)NEXP * CDIM * HDIM * 2;    // 37.7 MB
    bf16_t* hws = (bf16_t*)(w + off); off += (size_t)SLOTS * HDIM * 2;          // 50.3 MB
    int* counts   = (int*)(w + off);
    int* curs     = counts + NEXP;
    int* tile_e   = counts + 2 * NEXP;
    int* tile_m0  = tile_e + MAXT;
    int* tile_end = tile_m0 + MAXT;
    int* eidx     = tile_end + MAXT;
    int* tmap     = eidx + SLOTS;
    float* egate  = (float*)(tmap + SLOTS);
    float* gmap   = egate + SLOTS;

    hipMemsetAsync(counts, 0, NEXP * sizeof(int), stream);
    hipMemsetAsync(out, 0, (size_t)NT * CDIM * sizeof(float), stream);

    convert_x_kernel<<<NT * CDIM / 4 / 256, 256, 0, stream>>>(x, xb);
    transpose_convert_kernel<CDIM, HDIM>
        <<<dim3(HDIM / 32, CDIM / 32, NEXP), dim3(32, 8), 0, stream>>>(w1, w1t);
    transpose_convert_kernel<HDIM, CDIM>
        <<<dim3(CDIM / 32, HDIM / 32, NEXP), dim3(32, 8), 0, stream>>>(w2, w2t);
    router_kernel<<<NT, 64, 0, stream>>>(x, wg, eidx, egate, counts);
    plan_kernel<<<1, 64, 0, stream>>>(counts, curs, tile_e, tile_m0, tile_end);
    scatter_kernel<<<NT / 256, 256, 0, stream>>>(eidx, egate, curs, tmap, gmap);

    moe_gemm_kernel<CDIM, HDIM, true>
        <<<dim3(MAXT, HDIM / 128), 256, 0, stream>>>(
            xb, w1t, b1, tile_e, tile_m0, tile_end, tmap, gmap, hws, nullptr);
    moe_gemm_kernel<HDIM, CDIM, false>
        <<<dim3(MAXT, CDIM / 128), 256, 0, stream>>>(
            hws, w2t, b2, tile_e, tile_m0, tile_end, tmap, gmap, nullptr, out);
}

// Round 2
// 549.880 us; speedup vs baseline: 1.0246x; 1.0246x over previous
//
#include <hip/hip_runtime.h>
#include <hip/hip_bf16.h>
#include <cmath>

#define NT    4096            // B*T tokens
#define CDIM  768
#define HDIM  3072
#define NEXP  8
#define SLOTS (NT * 2)        // top-2 -> 8192 (token,expert) pairs, exact
#define MAXT  72              // max M-tiles: 8192/128 + 8 partial tiles

typedef __bf16 bf16_t;
typedef __bf16 bf16x8 __attribute__((ext_vector_type(8)));
typedef float  f32x4  __attribute__((ext_vector_type(4)));

// async global->LDS, 16B per lane; LDS dest = wave-uniform base + lane*16
__device__ __forceinline__ void glds16(const void* g, void* l) {
    __builtin_amdgcn_global_load_lds(
        (const __attribute__((address_space(1))) void*)g,
        (__attribute__((address_space(3))) void*)l, 16, 0, 0);
}

// ---------- W fp32 (E,R,CC) -> bf16 transposed (E,CC,R) ----------
template<int R, int CC>
__global__ void transpose_convert_kernel(const float* __restrict__ in, bf16_t* __restrict__ out) {
    __shared__ float tile[32][33];
    int e = blockIdx.z;
    int c0 = blockIdx.x * 32, r0 = blockIdx.y * 32;
    const float* src = in + (size_t)e * R * CC;
    bf16_t* dst = out + (size_t)e * R * CC;
    int tx = threadIdx.x, ty = threadIdx.y;    // (32,8)
    #pragma unroll
    for (int i = 0; i < 32; i += 8)
        tile[ty + i][tx] = src[(size_t)(r0 + ty + i) * CC + c0 + tx];
    __syncthreads();
    #pragma unroll
    for (int i = 0; i < 32; i += 8)
        dst[(size_t)(c0 + ty + i) * R + r0 + tx] = (bf16_t)tile[tx][ty + i];
}

// ---------- router (fused x->bf16 convert): fp32 logits, softmax, top-2 ----------
__global__ __launch_bounds__(256)
void router_kernel(const float* __restrict__ x, const float* __restrict__ wg,
                   bf16_t* __restrict__ xb,
                   int* __restrict__ eidx, float* __restrict__ egate,
                   int* __restrict__ counts) {
    int lane = threadIdx.x & 63, wid = threadIdx.x >> 6;
    int t = blockIdx.x * 4 + wid;              // one wave per token
    const float* xr = x + (size_t)t * CDIM;
    float acc[NEXP];
    #pragma unroll
    for (int e = 0; e < NEXP; e++) acc[e] = 0.f;
    #pragma unroll
    for (int i = 0; i < CDIM / 256; i++) {     // 3 float4 per lane
        int c = (i * 64 + lane) * 4;
        float4 v = *reinterpret_cast<const float4*>(xr + c);
        union { bf16_t h[4]; uint2 u; } un;
        un.h[0] = (bf16_t)v.x; un.h[1] = (bf16_t)v.y;
        un.h[2] = (bf16_t)v.z; un.h[3] = (bf16_t)v.w;
        *reinterpret_cast<uint2*>(xb + (size_t)t * CDIM + c) = un.u;
        float vv[4] = {v.x, v.y, v.z, v.w};
        #pragma unroll
        for (int j = 0; j < 4; j++)
            #pragma unroll
            for (int e = 0; e < NEXP; e++)
                acc[e] += vv[j] * wg[(c + j) * NEXP + e];
    }
    #pragma unroll
    for (int e = 0; e < NEXP; e++) {
        #pragma unroll
        for (int off = 32; off > 0; off >>= 1)
            acc[e] += __shfl_xor(acc[e], off, 64);
    }
    if (lane == 0) {
        float mx = acc[0];
        #pragma unroll
        for (int e = 1; e < NEXP; e++) mx = fmaxf(mx, acc[e]);
        float p[NEXP], s = 0.f;
        #pragma unroll
        for (int e = 0; e < NEXP; e++) { p[e] = expf(acc[e] - mx); s += p[e]; }
        float inv = 1.f / s;
        int i0 = 0;
        #pragma unroll
        for (int e = 1; e < NEXP; e++) if (p[e] > p[i0]) i0 = e;   // ties -> lower idx, matches lax.top_k
        int i1 = (i0 == 0) ? 1 : 0;
        #pragma unroll
        for (int e = 0; e < NEXP; e++) if (e != i0 && p[e] > p[i1]) i1 = e;
        eidx[t * 2]      = i0;  eidx[t * 2 + 1] = i1;
        egate[t * 2]     = p[i0] * inv;
        egate[t * 2 + 1] = p[i1] * inv;
        atomicAdd(&counts[i0], 1);
        atomicAdd(&counts[i1], 1);
    }
}

// ---------- plan: prefix sums + M-tile table, parallel over 128 threads ----------
__global__ void plan_kernel(const int* __restrict__ counts, int* __restrict__ curs,
                            int* __restrict__ tile_e, int* __restrict__ tile_m0,
                            int* __restrict__ tile_end) {
    int t = threadIdx.x;                        // 128 threads, 1 block
    int off = 0, nt = 0;
    int te = -1, tm0 = 0, tend = 0;
    #pragma unroll
    for (int e = 0; e < NEXP; e++) {
        int ne = counts[e];
        if (t == e) curs[t] = off;
        int ntile = (ne + 127) >> 7;
        if (t >= nt && t < nt + ntile) { te = e; tm0 = off + (t - nt) * 128; tend = off + ne; }
        nt += ntile;
        off += ne;
    }
    if (t < MAXT) { tile_e[t] = te; tile_m0[t] = tm0; tile_end[t] = tend; }
}

// ---------- scatter tokens into per-expert contiguous slots ----------
__global__ void scatter_kernel(const int* __restrict__ eidx, const float* __restrict__ egate,
                               int* __restrict__ curs, int* __restrict__ tmap,
                               float* __restrict__ gmap) {
    int t = blockIdx.x * blockDim.x + threadIdx.x;
    if (t >= NT) return;
    #pragma unroll
    for (int s = 0; s < 2; s++) {
        int e = eidx[t * 2 + s];
        int p = atomicAdd(&curs[e], 1);
        tmap[p] = t;
        gmap[p] = egate[t * 2 + s];
    }
}

// ---------- grouped GEMM, 128x128 tile, m97-style global_load_lds staging ----------
// FIRST: h[pos][n] = relu(bf16(X[tmap[pos]]) @ W1t[e] + b1[e])   (KDIM=768,  NDIM=3072)
// !FIRST: out[tmap[pos]][n] += gmap[pos]*(h[pos] @ W2t[e] + b2[e]) (KDIM=3072, NDIM=768, split-K)
template<int KDIM, int NDIM, bool FIRST, int KSLICES>
__global__ __launch_bounds__(256)
void moe_gemm_kernel(const bf16_t* __restrict__ Asrc, const bf16_t* __restrict__ Wt,
                     const float* __restrict__ bias,
                     const int* __restrict__ tile_e, const int* __restrict__ tile_m0,
                     const int* __restrict__ tile_end,
                     const int* __restrict__ tmap, const float* __restrict__ gmap,
                     bf16_t* __restrict__ hout, float* __restrict__ out) {
    int mt = blockIdx.x;
    int e = tile_e[mt];
    if (e < 0) return;
    int m0 = tile_m0[mt];
    int rend = tile_end[mt];
    int n0 = blockIdx.y * 128;
    constexpr int KS = KDIM / KSLICES;
    int kb = blockIdx.z * KS;

    // unpadded [128][32] bf16 (8KB each) — required by global_load_lds lane mapping
    __shared__ __attribute__((aligned(16))) bf16_t As[128 * 32];
    __shared__ __attribute__((aligned(16))) bf16_t Bs[128 * 32];

    int tid = threadIdx.x, lane = tid & 63, wid = tid >> 6;

    const bf16_t* aPtr[2];
    const bf16_t* bPtr[2];
    bf16_t* ldsA[2];
    bf16_t* ldsB[2];
    #pragma unroll
    for (int it = 0; it < 2; it++) {
        int region = wid * 2 + it;             // 8 regions of 16 rows
        int row = region * 16 + (lane >> 2);
        int kk = (lane & 3) * 8;               // 16B chunk within 64B row
        int pos = m0 + row;
        if (pos > rend - 1) pos = rend - 1;    // clamp: duplicate row, masked in epilogue
        int arow = FIRST ? tmap[pos] : pos;
        aPtr[it] = Asrc + (size_t)arow * KDIM + kb + kk;
        bPtr[it] = Wt + ((size_t)e * NDIM + n0 + row) * KDIM + kb + kk;
        ldsA[it] = As + region * 512;          // wave-uniform LDS base (1024B region)
        ldsB[it] = Bs + region * 512;
    }

    int wm = (wid >> 1) * 64, wn = (wid & 1) * 64;
    int q = lane >> 4, mr = lane & 15;
    int aOff = (wm + mr) * 32 + q * 8;
    int bOff = (wn + mr) * 32 + q * 8;

    f32x4 acc[4][4];
    #pragma unroll
    for (int i = 0; i < 4; i++)
        #pragma unroll
        for (int j = 0; j < 4; j++)
            acc[i][j] = (f32x4){0.f, 0.f, 0.f, 0.f};

    for (int k0 = 0; k0 < KS; k0 += 32) {
        #pragma unroll
        for (int it = 0; it < 2; it++) {
            glds16(aPtr[it] + k0, ldsA[it]);
            glds16(bPtr[it] + k0, ldsB[it]);
        }
        __syncthreads();    // compiler emits vmcnt(0) drain before barrier
        bf16x8 af[4], bfr[4];
        #pragma unroll
        for (int ti = 0; ti < 4; ti++) af[ti]  = *reinterpret_cast<const bf16x8*>(&As[aOff + ti * 16 * 32]);
        #pragma unroll
        for (int tj = 0; tj < 4; tj++) bfr[tj] = *reinterpret_cast<const bf16x8*>(&Bs[bOff + tj * 16 * 32]);
        #pragma unroll
        for (int ti = 0; ti < 4; ti++)
            #pragma unroll
            for (int tj = 0; tj < 4; tj++)
                acc[ti][tj] = __builtin_amdgcn_mfma_f32_16x16x32_bf16(af[ti], bfr[tj], acc[ti][tj], 0, 0, 0);
        __syncthreads();
    }

    // epilogue: D[row=q*4+r][col=mr] per 16x16 tile
    const float* be = bias + (size_t)e * NDIM;
    #pragma unroll
    for (int ti = 0; ti < 4; ti++) {
        #pragma unroll
        for (int r = 0; r < 4; r++) {
            int pos = m0 + wm + ti * 16 + q * 4 + r;
            if (pos < rend) {
                if (FIRST) {
                    bf16_t* hrow = hout + (size_t)pos * NDIM;
                    #pragma unroll
                    for (int tj = 0; tj < 4; tj++) {
                        int gcol = n0 + wn + tj * 16 + mr;
                        float v = acc[ti][tj][r] + be[gcol];
                        hrow[gcol] = (bf16_t)fmaxf(v, 0.f);
                    }
                } else {
                    int t = tmap[pos];
                    float g = gmap[pos];
                    float* orow = out + (size_t)t * NDIM;
                    #pragma unroll
                    for (int tj = 0; tj < 4; tj++) {
                        int gcol = n0 + wn + tj * 16 + mr;
                        float v = acc[ti][tj][r] + (kb == 0 ? be[gcol] : 0.f);
                        atomicAdd(&orow[gcol], g * v);
                    }
                }
            }
        }
    }
}

extern "C" void kernel_launch(void* const* d_in, const int* in_sizes, int n_in,
                              void* d_out, int out_size, void* d_ws, size_t ws_size,
                              hipStream_t stream) {
    const float* x  = (const float*)d_in[0];
    const float* wg = (const float*)d_in[1];
    const float* w1 = (const float*)d_in[2];
    const float* b1 = (const float*)d_in[3];
    const float* w2 = (const float*)d_in[4];
    const float* b2 = (const float*)d_in[5];
    float* out = (float*)d_out;

    char* w = (char*)d_ws;
    size_t off = 0;
    bf16_t* xb  = (bf16_t*)(w + off); off += (size_t)NT * CDIM * 2;             // 6.3 MB
    bf16_t* w1t = (bf16_t*)(w + off); off += (size_t)NEXP * CDIM * HDIM * 2;    // 37.7 MB
    bf16_t* w2t = (bf16_t*)(w + off); off += (size_t)NEXP * CDIM * HDIM * 2;    // 37.7 MB
    bf16_t* hws = (bf16_t*)(w + off); off += (size_t)SLOTS * HDIM * 2;          // 50.3 MB
    int* counts   = (int*)(w + off);
    int* curs     = counts + NEXP;
    int* tile_e   = counts + 2 * NEXP;
    int* tile_m0  = tile_e + MAXT;
    int* tile_end = tile_m0 + MAXT;
    int* eidx     = tile_end + MAXT;
    int* tmap     = eidx + SLOTS;
    float* egate  = (float*)(tmap + SLOTS);
    float* gmap   = egate + SLOTS;

    hipMemsetAsync(counts, 0, NEXP * sizeof(int), stream);
    hipMemsetAsync(out, 0, (size_t)NT * CDIM * sizeof(float), stream);

    transpose_convert_kernel<CDIM, HDIM>
        <<<dim3(HDIM / 32, CDIM / 32, NEXP), dim3(32, 8), 0, stream>>>(w1, w1t);
    transpose_convert_kernel<HDIM, CDIM>
        <<<dim3(CDIM / 32, HDIM / 32, NEXP), dim3(32, 8), 0, stream>>>(w2, w2t);
    router_kernel<<<NT / 4, 256, 0, stream>>>(x, wg, xb, eidx, egate, counts);
    plan_kernel<<<1, 128, 0, stream>>>(counts, curs, tile_e, tile_m0, tile_end);
    scatter_kernel<<<NT / 256, 256, 0, stream>>>(eidx, egate, curs, tmap, gmap);

    moe_gemm_kernel<CDIM, HDIM, true, 1>
        <<<dim3(MAXT, HDIM / 128, 1), 256, 0, stream>>>(
            xb, w1t, b1, tile_e, tile_m0, tile_end, tmap, gmap, hws, nullptr);
    moe_gemm_kernel<HDIM, CDIM, false, 2>
        <<<dim3(MAXT, CDIM / 128, 2), 256, 0, stream>>>(
            hws, w2t, b2, tile_e, tile_m0, tile_end, tmap, gmap, nullptr, out);
}

// Round 3
// 528.449 us; speedup vs baseline: 1.0662x; 1.0406x over previous
//
#include <hip/hip_runtime.h>
#include <hip/hip_bf16.h>
#include <cmath>

#define NT    4096            // B*T tokens
#define CDIM  768
#define HDIM  3072
#define NEXP  8
#define SLOTS (NT * 2)        // top-2 -> 8192 (token,expert) pairs, exact
#define MAXT  72              // max M-tiles: 8192/128 + 8 partial tiles

typedef __bf16 bf16_t;
typedef __bf16 bf16x8 __attribute__((ext_vector_type(8)));
typedef float  f32x4  __attribute__((ext_vector_type(4)));

// async global->LDS, 16B per lane; LDS dest = wave-uniform base + lane*16
__device__ __forceinline__ void glds16(const void* g, void* l) {
    __builtin_amdgcn_global_load_lds(
        (const __attribute__((address_space(1))) void*)g,
        (__attribute__((address_space(3))) void*)l, 16, 0, 0);
}

// ---------- W fp32 (E,R,CC) -> bf16 transposed (E,CC,R), 64x64 tiles ----------
template<int R, int CC>
__global__ __launch_bounds__(256)
void transpose_convert_kernel(const float* __restrict__ in, bf16_t* __restrict__ out) {
    __shared__ float tile[64][68];
    int e = blockIdx.z;
    int c0 = blockIdx.x * 64, r0 = blockIdx.y * 64;
    const float* src = in + (size_t)e * R * CC;
    bf16_t* dst = out + (size_t)e * R * CC;
    int t = threadIdx.x;
    int c4 = (t & 15) * 4, rr = t >> 4;
    #pragma unroll
    for (int i = 0; i < 4; i++) {
        int r = rr + i * 16;
        float4 v = *reinterpret_cast<const float4*>(&src[(size_t)(r0 + r) * CC + c0 + c4]);
        tile[r][c4 + 0] = v.x; tile[r][c4 + 1] = v.y;
        tile[r][c4 + 2] = v.z; tile[r][c4 + 3] = v.w;
    }
    __syncthreads();
    #pragma unroll
    for (int i = 0; i < 4; i++) {
        int cc = rr + i * 16;
        int r4 = (t & 15) * 4;
        union { bf16_t h[4]; uint2 u; } un;
        un.h[0] = (bf16_t)tile[r4 + 0][cc]; un.h[1] = (bf16_t)tile[r4 + 1][cc];
        un.h[2] = (bf16_t)tile[r4 + 2][cc]; un.h[3] = (bf16_t)tile[r4 + 3][cc];
        *reinterpret_cast<uint2*>(&dst[(size_t)(c0 + cc) * R + r0 + r4]) = un.u;
    }
}

// ---------- router (fused x->bf16 convert): fp32 logits, softmax, top-2 ----------
__global__ __launch_bounds__(256)
void router_kernel(const float* __restrict__ x, const float* __restrict__ wg,
                   bf16_t* __restrict__ xb,
                   int* __restrict__ eidx, float* __restrict__ egate,
                   int* __restrict__ counts) {
    int lane = threadIdx.x & 63, wid = threadIdx.x >> 6;
    int t = blockIdx.x * 4 + wid;              // one wave per token
    const float* xr = x + (size_t)t * CDIM;
    float acc[NEXP];
    #pragma unroll
    for (int e = 0; e < NEXP; e++) acc[e] = 0.f;
    #pragma unroll
    for (int i = 0; i < CDIM / 256; i++) {     // 3 float4 per lane
        int c = (i * 64 + lane) * 4;
        float4 v = *reinterpret_cast<const float4*>(xr + c);
        union { bf16_t h[4]; uint2 u; } un;
        un.h[0] = (bf16_t)v.x; un.h[1] = (bf16_t)v.y;
        un.h[2] = (bf16_t)v.z; un.h[3] = (bf16_t)v.w;
        *reinterpret_cast<uint2*>(xb + (size_t)t * CDIM + c) = un.u;
        float vv[4] = {v.x, v.y, v.z, v.w};
        #pragma unroll
        for (int j = 0; j < 4; j++)
            #pragma unroll
            for (int e = 0; e < NEXP; e++)
                acc[e] += vv[j] * wg[(c + j) * NEXP + e];
    }
    #pragma unroll
    for (int e = 0; e < NEXP; e++) {
        #pragma unroll
        for (int off = 32; off > 0; off >>= 1)
            acc[e] += __shfl_xor(acc[e], off, 64);
    }
    if (lane == 0) {
        float mx = acc[0];
        #pragma unroll
        for (int e = 1; e < NEXP; e++) mx = fmaxf(mx, acc[e]);
        float p[NEXP], s = 0.f;
        #pragma unroll
        for (int e = 0; e < NEXP; e++) { p[e] = expf(acc[e] - mx); s += p[e]; }
        float inv = 1.f / s;
        int i0 = 0;
        #pragma unroll
        for (int e = 1; e < NEXP; e++) if (p[e] > p[i0]) i0 = e;   // ties -> lower idx, matches lax.top_k
        int i1 = (i0 == 0) ? 1 : 0;
        #pragma unroll
        for (int e = 0; e < NEXP; e++) if (e != i0 && p[e] > p[i1]) i1 = e;
        eidx[t * 2]      = i0;  eidx[t * 2 + 1] = i1;
        egate[t * 2]     = p[i0] * inv;
        egate[t * 2 + 1] = p[i1] * inv;
        atomicAdd(&counts[i0], 1);
        atomicAdd(&counts[i1], 1);
    }
}

// ---------- plan: prefix sums + M-tile table, parallel over 128 threads ----------
__global__ void plan_kernel(const int* __restrict__ counts, int* __restrict__ curs,
                            int* __restrict__ tile_e, int* __restrict__ tile_m0,
                            int* __restrict__ tile_end) {
    int t = threadIdx.x;                        // 128 threads, 1 block
    int off = 0, nt = 0;
    int te = -1, tm0 = 0, tend = 0;
    #pragma unroll
    for (int e = 0; e < NEXP; e++) {
        int ne = counts[e];
        if (t == e) curs[t] = off;
        int ntile = (ne + 127) >> 7;
        if (t >= nt && t < nt + ntile) { te = e; tm0 = off + (t - nt) * 128; tend = off + ne; }
        nt += ntile;
        off += ne;
    }
    if (t < MAXT) { tile_e[t] = te; tile_m0[t] = tm0; tile_end[t] = tend; }
}

// ---------- scatter tokens into per-expert contiguous slots ----------
__global__ void scatter_kernel(const int* __restrict__ eidx, const float* __restrict__ egate,
                               int* __restrict__ curs, int* __restrict__ tmap,
                               float* __restrict__ gmap) {
    int t = blockIdx.x * blockDim.x + threadIdx.x;
    if (t >= NT) return;
    #pragma unroll
    for (int s = 0; s < 2; s++) {
        int e = eidx[t * 2 + s];
        int p = atomicAdd(&curs[e], 1);
        tmap[p] = t;
        gmap[p] = egate[t * 2 + s];
    }
}

// ---------- grouped GEMM, 128x128 tile, BK=64, XOR-swizzled LDS, XCD swizzle ----------
// FIRST: h[pos][n] = relu(bf16(X[tmap[pos]]) @ W1t[e] + b1[e])   (KDIM=768,  NDIM=3072)
// !FIRST: out[tmap[pos]][n] += gmap[pos]*(h[pos] @ W2t[e] + b2[e]) (KDIM=3072, NDIM=768, split-K)
template<int KDIM, int NDIM, bool FIRST, int KSLICES>
__global__ __launch_bounds__(256, 3)
void moe_gemm_kernel(const bf16_t* __restrict__ Asrc, const bf16_t* __restrict__ Wt,
                     const float* __restrict__ bias,
                     const int* __restrict__ tile_e, const int* __restrict__ tile_m0,
                     const int* __restrict__ tile_end,
                     const int* __restrict__ tmap, const float* __restrict__ gmap,
                     bf16_t* __restrict__ hout, float* __restrict__ out) {
    // XCD swizzle: co-locate the 8 consecutive M-tiles sharing a B-tile on one XCD
    // (ids == same mod 8 under round-robin). Tail group (not mult of 64) left identity.
    int gx = gridDim.x;
    int f = blockIdx.y * gx + blockIdx.x;
    int total = gx * gridDim.y, lim = total & ~63;
    int l = (f < lim) ? ((f & ~63) | ((f & 7) << 3) | ((f >> 3) & 7)) : f;
    int mt = l % gx;
    int n0 = (l / gx) * 128;

    int e = tile_e[mt];
    if (e < 0) return;
    int m0 = tile_m0[mt];
    int rend = tile_end[mt];
    constexpr int KS = KDIM / KSLICES;
    int kb = blockIdx.z * KS;

    // [128][64] bf16 (16KB each); rows XOR-swizzled in 16B chunks: slot s of row r
    // holds global chunk s ^ (r&7)  -> conflict-free b128 fragment reads.
    __shared__ __attribute__((aligned(16))) bf16_t As[128 * 64];
    __shared__ __attribute__((aligned(16))) bf16_t Bs[128 * 64];

    int tid = threadIdx.x, lane = tid & 63, wid = tid >> 6;

    // staging: 16 regions of 8 rows; wave w serves regions w*4..w*4+3 for A and B
    int rsub = lane >> 3;                  // row within 8-row group
    int gcol8 = (lane & 7) ^ rsub;         // swizzled global 16B-chunk index
    const bf16_t* aPtr[4];
    const bf16_t* bPtr[4];
    bf16_t* ldsA[4];
    bf16_t* ldsB[4];
    #pragma unroll
    for (int i = 0; i < 4; i++) {
        int region = wid * 4 + i;
        int row = region * 8 + rsub;
        int pos = m0 + row;
        if (pos > rend - 1) pos = rend - 1;    // clamp: duplicate row, masked in epilogue
        int arow = FIRST ? tmap[pos] : pos;
        aPtr[i] = Asrc + (size_t)arow * KDIM + kb + gcol8 * 8;
        bPtr[i] = Wt + ((size_t)e * NDIM + n0 + row) * KDIM + kb + gcol8 * 8;
        ldsA[i] = As + region * 512;           // 1KB wave-uniform region
        ldsB[i] = Bs + region * 512;
    }

    int wm = (wid >> 1) * 64, wn = (wid & 1) * 64;
    int q = lane >> 4, mr = lane & 15;
    int x = mr & 7;                            // fragment-read XOR term

    f32x4 acc[4][4];
    #pragma unroll
    for (int i = 0; i < 4; i++)
        #pragma unroll
        for (int j = 0; j < 4; j++)
            acc[i][j] = (f32x4){0.f, 0.f, 0.f, 0.f};

    for (int k0 = 0; k0 < KS; k0 += 64) {
        #pragma unroll
        for (int i = 0; i < 4; i++) {
            glds16(aPtr[i] + k0, ldsA[i]);
            glds16(bPtr[i] + k0, ldsB[i]);
        }
        __syncthreads();    // compiler emits vmcnt(0) drain before barrier
        #pragma unroll
        for (int kh = 0; kh < 2; kh++) {
            int sA = ((q + kh * 4) ^ x) * 8;
            bf16x8 af[4], bfr[4];
            #pragma unroll
            for (int ti = 0; ti < 4; ti++)
                af[ti] = *reinterpret_cast<const bf16x8*>(&As[(wm + ti * 16 + mr) * 64 + sA]);
            #pragma unroll
            for (int tj = 0; tj < 4; tj++)
                bfr[tj] = *reinterpret_cast<const bf16x8*>(&Bs[(wn + tj * 16 + mr) * 64 + sA]);
            #pragma unroll
            for (int ti = 0; ti < 4; ti++)
                #pragma unroll
                for (int tj = 0; tj < 4; tj++)
                    acc[ti][tj] = __builtin_amdgcn_mfma_f32_16x16x32_bf16(af[ti], bfr[tj], acc[ti][tj], 0, 0, 0);
        }
        __syncthreads();
    }

    // epilogue: D[row=q*4+r][col=mr] per 16x16 tile
    const float* be = bias + (size_t)e * NDIM;
    #pragma unroll
    for (int ti = 0; ti < 4; ti++) {
        #pragma unroll
        for (int r = 0; r < 4; r++) {
            int pos = m0 + wm + ti * 16 + q * 4 + r;
            if (pos < rend) {
                if (FIRST) {
                    bf16_t* hrow = hout + (size_t)pos * NDIM;
                    #pragma unroll
                    for (int tj = 0; tj < 4; tj++) {
                        int gcol = n0 + wn + tj * 16 + mr;
                        float v = acc[ti][tj][r] + be[gcol];
                        hrow[gcol] = (bf16_t)fmaxf(v, 0.f);
                    }
                } else {
                    int t = tmap[pos];
                    float g = gmap[pos];
                    float* orow = out + (size_t)t * NDIM;
                    #pragma unroll
                    for (int tj = 0; tj < 4; tj++) {
                        int gcol = n0 + wn + tj * 16 + mr;
                        float v = acc[ti][tj][r] + (kb == 0 ? be[gcol] : 0.f);
                        atomicAdd(&orow[gcol], g * v);
                    }
                }
            }
        }
    }
}

extern "C" void kernel_launch(void* const* d_in, const int* in_sizes, int n_in,
                              void* d_out, int out_size, void* d_ws, size_t ws_size,
                              hipStream_t stream) {
    const float* x  = (const float*)d_in[0];
    const float* wg = (const float*)d_in[1];
    const float* w1 = (const float*)d_in[2];
    const float* b1 = (const float*)d_in[3];
    const float* w2 = (const float*)d_in[4];
    const float* b2 = (const float*)d_in[5];
    float* out = (float*)d_out;

    char* w = (char*)d_ws;
    size_t off = 0;
    bf16_t* xb  = (bf16_t*)(w + off); off += (size_t)NT * CDIM * 2;             // 6.3 MB
    bf16_t* w1t = (bf16_t*)(w + off); off += (size_t)NEXP * CDIM * HDIM * 2;    // 37.7 MB
    bf16_t* w2t = (bf16_t*)(w + off); off += (size_t)NEXP * CDIM * HDIM * 2;    // 37.7 MB
    bf16_t* hws = (bf16_t*)(w + off); off += (size_t)SLOTS * HDIM * 2;          // 50.3 MB
    int* counts   = (int*)(w + off);
    int* curs     = counts + NEXP;
    int* tile_e   = counts + 2 * NEXP;
    int* tile_m0  = tile_e + MAXT;
    int* tile_end = tile_m0 + MAXT;
    int* eidx     = tile_end + MAXT;
    int* tmap     = eidx + SLOTS;
    float* egate  = (float*)(tmap + SLOTS);
    float* gmap   = egate + SLOTS;

    hipMemsetAsync(counts, 0, NEXP * sizeof(int), stream);
    hipMemsetAsync(out, 0, (size_t)NT * CDIM * sizeof(float), stream);

    transpose_convert_kernel<CDIM, HDIM>
        <<<dim3(HDIM / 64, CDIM / 64, NEXP), 256, 0, stream>>>(w1, w1t);
    transpose_convert_kernel<HDIM, CDIM>
        <<<dim3(CDIM / 64, HDIM / 64, NEXP), 256, 0, stream>>>(w2, w2t);
    router_kernel<<<NT / 4, 256, 0, stream>>>(x, wg, xb, eidx, egate, counts);
    plan_kernel<<<1, 128, 0, stream>>>(counts, curs, tile_e, tile_m0, tile_end);
    scatter_kernel<<<NT / 256, 256, 0, stream>>>(eidx, egate, curs, tmap, gmap);

    moe_gemm_kernel<CDIM, HDIM, true, 1>
        <<<dim3(MAXT, HDIM / 128, 1), 256, 0, stream>>>(
            xb, w1t, b1, tile_e, tile_m0, tile_end, tmap, gmap, hws, nullptr);
    moe_gemm_kernel<HDIM, CDIM, false, 2>
        <<<dim3(MAXT, CDIM / 128, 2), 256, 0, stream>>>(
            hws, w2t, b2, tile_e, tile_m0, tile_end, tmap, gmap, nullptr, out);
}

// Round 4
// 517.789 us; speedup vs baseline: 1.0881x; 1.0206x over previous
//
#include <hip/hip_runtime.h>
#include <hip/hip_bf16.h>
#include <cmath>

#define NT    4096            // B*T tokens
#define CDIM  768
#define HDIM  3072
#define NEXP  8
#define SLOTS (NT * 2)        // top-2 -> 8192 (token,expert) pairs, exact
#define TPE   10              // max M-tiles per expert (1280 tokens, ~8.5 sigma)

typedef __bf16 bf16_t;
typedef __bf16 bf16x8 __attribute__((ext_vector_type(8)));
typedef float  f32x4  __attribute__((ext_vector_type(4)));

// async global->LDS, 16B per lane; LDS dest = wave-uniform base + lane*16
__device__ __forceinline__ void glds16(const void* g, void* l) {
    __builtin_amdgcn_global_load_lds(
        (const __attribute__((address_space(1))) void*)g,
        (__attribute__((address_space(3))) void*)l, 16, 0, 0);
}

// ---------- W fp32 (E,R,CC) -> bf16 transposed (E,CC,R), 64x64 tiles ----------
template<int R, int CC>
__global__ __launch_bounds__(256)
void transpose_convert_kernel(const float* __restrict__ in, bf16_t* __restrict__ out) {
    __shared__ float tile[64][68];
    int e = blockIdx.z;
    int c0 = blockIdx.x * 64, r0 = blockIdx.y * 64;
    const float* src = in + (size_t)e * R * CC;
    bf16_t* dst = out + (size_t)e * R * CC;
    int t = threadIdx.x;
    int c4 = (t & 15) * 4, rr = t >> 4;
    #pragma unroll
    for (int i = 0; i < 4; i++) {
        int r = rr + i * 16;
        float4 v = *reinterpret_cast<const float4*>(&src[(size_t)(r0 + r) * CC + c0 + c4]);
        tile[r][c4 + 0] = v.x; tile[r][c4 + 1] = v.y;
        tile[r][c4 + 2] = v.z; tile[r][c4 + 3] = v.w;
    }
    __syncthreads();
    #pragma unroll
    for (int i = 0; i < 4; i++) {
        int cc = rr + i * 16;
        int r4 = (t & 15) * 4;
        union { bf16_t h[4]; uint2 u; } un;
        un.h[0] = (bf16_t)tile[r4 + 0][cc]; un.h[1] = (bf16_t)tile[r4 + 1][cc];
        un.h[2] = (bf16_t)tile[r4 + 2][cc]; un.h[3] = (bf16_t)tile[r4 + 3][cc];
        *reinterpret_cast<uint2*>(&dst[(size_t)(c0 + cc) * R + r0 + r4]) = un.u;
    }
}

// ---------- router (fused x->bf16 convert): fp32 logits, softmax, top-2 ----------
__global__ __launch_bounds__(256)
void router_kernel(const float* __restrict__ x, const float* __restrict__ wg,
                   bf16_t* __restrict__ xb,
                   int* __restrict__ eidx, float* __restrict__ egate,
                   int* __restrict__ counts) {
    int lane = threadIdx.x & 63, wid = threadIdx.x >> 6;
    int t = blockIdx.x * 4 + wid;              // one wave per token
    const float* xr = x + (size_t)t * CDIM;
    float acc[NEXP];
    #pragma unroll
    for (int e = 0; e < NEXP; e++) acc[e] = 0.f;
    #pragma unroll
    for (int i = 0; i < CDIM / 256; i++) {     // 3 float4 per lane
        int c = (i * 64 + lane) * 4;
        float4 v = *reinterpret_cast<const float4*>(xr + c);
        union { bf16_t h[4]; uint2 u; } un;
        un.h[0] = (bf16_t)v.x; un.h[1] = (bf16_t)v.y;
        un.h[2] = (bf16_t)v.z; un.h[3] = (bf16_t)v.w;
        *reinterpret_cast<uint2*>(xb + (size_t)t * CDIM + c) = un.u;
        float vv[4] = {v.x, v.y, v.z, v.w};
        #pragma unroll
        for (int j = 0; j < 4; j++)
            #pragma unroll
            for (int e = 0; e < NEXP; e++)
                acc[e] += vv[j] * wg[(c + j) * NEXP + e];
    }
    #pragma unroll
    for (int e = 0; e < NEXP; e++) {
        #pragma unroll
        for (int off = 32; off > 0; off >>= 1)
            acc[e] += __shfl_xor(acc[e], off, 64);
    }
    if (lane == 0) {
        float mx = acc[0];
        #pragma unroll
        for (int e = 1; e < NEXP; e++) mx = fmaxf(mx, acc[e]);
        float p[NEXP], s = 0.f;
        #pragma unroll
        for (int e = 0; e < NEXP; e++) { p[e] = expf(acc[e] - mx); s += p[e]; }
        float inv = 1.f / s;
        int i0 = 0;
        #pragma unroll
        for (int e = 1; e < NEXP; e++) if (p[e] > p[i0]) i0 = e;   // ties -> lower idx, matches lax.top_k
        int i1 = (i0 == 0) ? 1 : 0;
        #pragma unroll
        for (int e = 0; e < NEXP; e++) if (e != i0 && p[e] > p[i1]) i1 = e;
        eidx[t * 2]      = i0;  eidx[t * 2 + 1] = i1;
        egate[t * 2]     = p[i0] * inv;
        egate[t * 2 + 1] = p[i1] * inv;
        atomicAdd(&counts[i0], 1);
        atomicAdd(&counts[i1], 1);
    }
}

// ---------- plan: per-expert offsets (tiny) ----------
__global__ void plan_kernel(const int* __restrict__ counts, int* __restrict__ curs,
                            int* __restrict__ eoff, int* __restrict__ ecnt) {
    if (threadIdx.x != 0) return;
    int off = 0;
    for (int e = 0; e < NEXP; e++) {
        int ne = counts[e];
        eoff[e] = off; ecnt[e] = ne; curs[e] = off;
        off += ne;
    }
}

// ---------- scatter tokens into per-expert contiguous slots ----------
__global__ void scatter_kernel(const int* __restrict__ eidx, const float* __restrict__ egate,
                               int* __restrict__ curs, int* __restrict__ tmap,
                               float* __restrict__ gmap) {
    int t = blockIdx.x * blockDim.x + threadIdx.x;
    if (t >= NT) return;
    #pragma unroll
    for (int s = 0; s < 2; s++) {
        int e = eidx[t * 2 + s];
        int p = atomicAdd(&curs[e], 1);
        tmap[p] = t;
        gmap[p] = egate[t * 2 + s];
    }
}

// ---------- grouped GEMM, 128x128 tile, BK=64, dbuf LDS, expert<->XCD partition ----
// 1-D grid: h & 7 = expert (XCD under round-robin), h>>3 = local slot, nt fastest
// FIRST: h[pos][n] = relu(bf16(X[tmap[pos]]) @ W1t[e] + b1[e])   (KDIM=768,  NDIM=3072)
// !FIRST: out[tmap[pos]][n] += gmap[pos]*(h[pos] @ W2t[e] + b2[e]) (KDIM=3072, NDIM=768, split-K)
template<int KDIM, int NDIM, bool FIRST, int KSLICES>
__global__ __launch_bounds__(256, 2)
void moe_gemm_kernel(const bf16_t* __restrict__ Asrc, const bf16_t* __restrict__ Wt,
                     const float* __restrict__ bias,
                     const int* __restrict__ eoff, const int* __restrict__ ecnt,
                     const int* __restrict__ tmap, const float* __restrict__ gmap,
                     bf16_t* __restrict__ hout, float* __restrict__ out) {
    constexpr int KS = KDIM / KSLICES;
    constexpr int NTILES = NDIM / 128;           // 24 (GEMM1) / 6 (GEMM2)
    constexpr int NIT = KS / 64;                 // 12 / 24 (even)

    int h = blockIdx.x;
    int e = h & 7;
    int local = h >> 3;
    int j, nt, kb;
    if (FIRST) {
        j = local / NTILES; nt = local - j * NTILES; kb = 0;
    } else {
        j = local / (NTILES * KSLICES);
        int rem = local - j * (NTILES * KSLICES);
        int kz = rem / NTILES; nt = rem - kz * NTILES;
        kb = kz * KS;
    }
    int cnt = ecnt[e];
    if (j * 128 >= cnt) return;
    int m0 = eoff[e] + j * 128;
    int rend = eoff[e] + cnt;
    int n0 = nt * 128;

    // dbuf [2][128][64] bf16 (16KB each buf); rows XOR-swizzled in 16B chunks:
    // slot s of row r holds global chunk s ^ (r&7) -> conflict-free b128 reads.
    __shared__ __attribute__((aligned(16))) bf16_t As[2][128 * 64];
    __shared__ __attribute__((aligned(16))) bf16_t Bs[2][128 * 64];

    int tid = threadIdx.x, lane = tid & 63, wid = tid >> 6;

    // staging: 16 regions of 8 rows; wave w serves regions w*4..w*4+3 for A and B
    int rsub = lane >> 3;                  // row within 8-row group
    int gcol8 = (lane & 7) ^ rsub;         // swizzled global 16B-chunk index
    const bf16_t* aPtr[4];
    const bf16_t* bPtr[4];
    int regOff[4];
    #pragma unroll
    for (int i = 0; i < 4; i++) {
        int region = wid * 4 + i;
        int row = region * 8 + rsub;
        int pos = m0 + row;
        if (pos > rend - 1) pos = rend - 1;    // clamp: duplicate row, masked in epilogue
        int arow = FIRST ? tmap[pos] : pos;
        aPtr[i] = Asrc + (size_t)arow * KDIM + kb + gcol8 * 8;
        bPtr[i] = Wt + ((size_t)e * NDIM + n0 + row) * KDIM + kb + gcol8 * 8;
        regOff[i] = region * 512;              // 1KB wave-uniform region
    }

    int wm = (wid >> 1) * 64, wn = (wid & 1) * 64;
    int q = lane >> 4, mr = lane & 15;
    int x = mr & 7;                            // fragment-read XOR term

    f32x4 acc[4][4];
    #pragma unroll
    for (int i = 0; i < 4; i++)
        #pragma unroll
        for (int jj = 0; jj < 4; jj++)
            acc[i][jj] = (f32x4){0.f, 0.f, 0.f, 0.f};

    auto stage = [&](int buf, int k0) {
        #pragma unroll
        for (int i = 0; i < 4; i++) {
            glds16(aPtr[i] + k0, &As[buf][regOff[i]]);
            glds16(bPtr[i] + k0, &Bs[buf][regOff[i]]);
        }
    };
    auto compute = [&](int buf) {
        #pragma unroll
        for (int kh = 0; kh < 2; kh++) {
            int sA = ((q + kh * 4) ^ x) * 8;
            bf16x8 af[4], bfr[4];
            #pragma unroll
            for (int ti = 0; ti < 4; ti++)
                af[ti] = *reinterpret_cast<const bf16x8*>(&As[buf][(wm + ti * 16 + mr) * 64 + sA]);
            #pragma unroll
            for (int tj = 0; tj < 4; tj++)
                bfr[tj] = *reinterpret_cast<const bf16x8*>(&Bs[buf][(wn + tj * 16 + mr) * 64 + sA]);
            #pragma unroll
            for (int ti = 0; ti < 4; ti++)
                #pragma unroll
                for (int tj = 0; tj < 4; tj++)
                    acc[ti][tj] = __builtin_amdgcn_mfma_f32_16x16x32_bf16(af[ti], bfr[tj], acc[ti][tj], 0, 0, 0);
        }
    };

    stage(0, 0);                                // prologue
    for (int it = 0; it < NIT; it += 2) {
        __syncthreads();                        // drains vmcnt(0): buf0 ready
        if (it + 1 < NIT) stage(1, (it + 1) * 64);   // prefetch has full compute phase in flight
        compute(0);
        __syncthreads();                        // buf1 ready
        if (it + 2 < NIT) stage(0, (it + 2) * 64);
        compute(1);
    }

    // epilogue: D[row=q*4+r][col=mr] per 16x16 tile
    const float* be = bias + (size_t)e * NDIM;
    #pragma unroll
    for (int ti = 0; ti < 4; ti++) {
        #pragma unroll
        for (int r = 0; r < 4; r++) {
            int pos = m0 + wm + ti * 16 + q * 4 + r;
            if (pos < rend) {
                if (FIRST) {
                    bf16_t* hrow = hout + (size_t)pos * NDIM;
                    #pragma unroll
                    for (int tj = 0; tj < 4; tj++) {
                        int gcol = n0 + wn + tj * 16 + mr;
                        float v = acc[ti][tj][r] + be[gcol];
                        hrow[gcol] = (bf16_t)fmaxf(v, 0.f);
                    }
                } else {
                    int t = tmap[pos];
                    float g = gmap[pos];
                    float* orow = out + (size_t)t * NDIM;
                    #pragma unroll
                    for (int tj = 0; tj < 4; tj++) {
                        int gcol = n0 + wn + tj * 16 + mr;
                        float v = acc[ti][tj][r] + (kb == 0 ? be[gcol] : 0.f);
                        atomicAdd(&orow[gcol], g * v);
                    }
                }
            }
        }
    }
}

extern "C" void kernel_launch(void* const* d_in, const int* in_sizes, int n_in,
                              void* d_out, int out_size, void* d_ws, size_t ws_size,
                              hipStream_t stream) {
    const float* x  = (const float*)d_in[0];
    const float* wg = (const float*)d_in[1];
    const float* w1 = (const float*)d_in[2];
    const float* b1 = (const float*)d_in[3];
    const float* w2 = (const float*)d_in[4];
    const float* b2 = (const float*)d_in[5];
    float* out = (float*)d_out;

    char* w = (char*)d_ws;
    size_t off = 0;
    bf16_t* xb  = (bf16_t*)(w + off); off += (size_t)NT * CDIM * 2;             // 6.3 MB
    bf16_t* w1t = (bf16_t*)(w + off); off += (size_t)NEXP * CDIM * HDIM * 2;    // 37.7 MB
    bf16_t* w2t = (bf16_t*)(w + off); off += (size_t)NEXP * CDIM * HDIM * 2;    // 37.7 MB
    bf16_t* hws = (bf16_t*)(w + off); off += (size_t)SLOTS * HDIM * 2;          // 50.3 MB
    int* counts   = (int*)(w + off);
    int* curs     = counts + NEXP;
    int* eoff     = counts + 2 * NEXP;
    int* ecnt     = counts + 3 * NEXP;
    int* eidx     = counts + 4 * NEXP;
    int* tmap     = eidx + SLOTS;
    float* egate  = (float*)(tmap + SLOTS);
    float* gmap   = egate + SLOTS;

    hipMemsetAsync(counts, 0, NEXP * sizeof(int), stream);
    hipMemsetAsync(out, 0, (size_t)NT * CDIM * sizeof(float), stream);

    transpose_convert_kernel<CDIM, HDIM>
        <<<dim3(HDIM / 64, CDIM / 64, NEXP), 256, 0, stream>>>(w1, w1t);
    transpose_convert_kernel<HDIM, CDIM>
        <<<dim3(CDIM / 64, HDIM / 64, NEXP), 256, 0, stream>>>(w2, w2t);
    router_kernel<<<NT / 4, 256, 0, stream>>>(x, wg, xb, eidx, egate, counts);
    plan_kernel<<<1, 64, 0, stream>>>(counts, curs, eoff, ecnt);
    scatter_kernel<<<NT / 256, 256, 0, stream>>>(eidx, egate, curs, tmap, gmap);

    // 1-D grids: 8 experts x TPE tiles x NTILES (x KSLICES)
    moe_gemm_kernel<CDIM, HDIM, true, 1>
        <<<8 * TPE * (HDIM / 128), 256, 0, stream>>>(
            xb, w1t, b1, eoff, ecnt, tmap, gmap, hws, nullptr);
    moe_gemm_kernel<HDIM, CDIM, false, 2>
        <<<8 * TPE * (CDIM / 128) * 2, 256, 0, stream>>>(
            hws, w2t, b2, eoff, ecnt, tmap, gmap, nullptr, out);
}